// Round 4
// baseline (584.399 us; speedup 1.0000x reference)
//
#include <hip/hip_runtime.h>

#define QLEN 512
#define MLEN 512
#define KLEN 1024
#define BB   8
#define DMODEL 1024
#define NH   16
#define HD   64
#define NF   384
#define ATT_SCALE 0.125f
#define EPSV 1e-5f

typedef float v4f __attribute__((ext_vector_type(4)));
typedef short bf16x8 __attribute__((ext_vector_type(8)));
typedef unsigned int u32x4 __attribute__((ext_vector_type(4)));
typedef unsigned short u16x8 __attribute__((ext_vector_type(8)));

__device__ __forceinline__ unsigned short f2bf(float f) {
    unsigned int x = __builtin_bit_cast(unsigned int, f);
    x += 0x7fffu + ((x >> 16) & 1u);
    return (unsigned short)(x >> 16);
}

__device__ __forceinline__ void gll16(const void* g, void* l) {
    __builtin_amdgcn_global_load_lds(
        (const __attribute__((address_space(1))) unsigned int*)g,
        (__attribute__((address_space(3))) unsigned int*)l, 16, 0, 0);
}

// ---------------------------------------------------------------------------
// Fused f32->bf16 converts: mems+h -> cbf (c matrix), weights -> bf16 scratch
// ---------------------------------------------------------------------------
__global__ __launch_bounds__(256)
void cvt_all_kernel(const float* __restrict__ h, const float* __restrict__ mems,
                    const float* __restrict__ Wq, const float* __restrict__ Wkv,
                    const float* __restrict__ Wo,
                    unsigned short* __restrict__ cbf, unsigned short* __restrict__ wqb,
                    unsigned short* __restrict__ wkvb, unsigned short* __restrict__ wob)
{
    int blk = blockIdx.x;
    const float* src; unsigned short* dst; int base;
    if (blk < 4096)       { src = mems; dst = cbf;           base = blk; }
    else if (blk < 8192)  { src = h;    dst = cbf + 4194304; base = blk - 4096; }
    else if (blk < 9216)  { src = Wq;   dst = wqb;           base = blk - 8192; }
    else if (blk < 11264) { src = Wkv;  dst = wkvb;          base = blk - 9216; }
    else                  { src = Wo;   dst = wob;           base = blk - 11264; }
    int i = (base * 256 + threadIdx.x) * 4;
    v4f v = *(const v4f*)(src + i);
    unsigned int p0, p1;
    asm("v_cvt_pk_bf16_f32 %0, %1, %2" : "=v"(p0) : "v"(v[0]), "v"(v[1]));
    asm("v_cvt_pk_bf16_f32 %0, %1, %2" : "=v"(p1) : "v"(v[2]), "v"(v[3]));
    uint2 u; u.x = p0; u.y = p1;
    *(uint2*)(dst + i) = u;
}

// ---------------------------------------------------------------------------
// Pure MFMA GEMM, 128x128 tile, BK=64, 4 waves (each 64x64 = 4x4 frags).
// A,B bf16 row-major [.][1024]. LDS staged via global_load_lds with
// pre-swizzled source chunks (chunk ^ row&7); reads use same XOR.
// MODE 0: out = q_raw bf16 [4096][1024]
// MODE 1: outK = k_raw bf16 [8192][1024], outV = v_raw bf16 [8192][1024]
// MODE 2: xo = f32 [4096][1024] = C + hres
// ---------------------------------------------------------------------------
template<int MODE>
__global__ __launch_bounds__(256)
void mm128_kernel(const unsigned short* __restrict__ Abf,
                  const unsigned short* __restrict__ Bbf,
                  const float* __restrict__ hres,
                  unsigned short* __restrict__ outK,
                  unsigned short* __restrict__ outV,
                  float* __restrict__ xo)
{
    __shared__ unsigned short As[128 * 64];
    __shared__ unsigned short Bs[128 * 64];

    const int t  = threadIdx.x;
    const int w  = t >> 6;
    const int l  = t & 63;
    const int lj = l & 15;
    const int lg = l >> 4;
    const int m0 = blockIdx.x * 128;
    const int n0 = blockIdx.y * 128;
    const int wr = w >> 1, wc = w & 1;
    const int rsub = l >> 3;                      // 0..7
    const int csw  = ((l & 7) ^ rsub) * 16;       // swizzled source chunk

    v4f acc[4][4] = {};

    for (int s = 0; s < 16; ++s) {
        const int k0b = s * 128;
        __syncthreads();
        #pragma unroll
        for (int u = 0; u < 4; ++u) {
            int ra = w * 32 + u * 8;
            gll16((const char*)Abf + (size_t)(m0 + ra + rsub) * 2048 + k0b + csw,
                  (char*)As + ra * 128);
            gll16((const char*)Bbf + (size_t)(n0 + ra + rsub) * 2048 + k0b + csw,
                  (char*)Bs + ra * 128);
        }
        __syncthreads();
        #pragma unroll
        for (int ks = 0; ks < 2; ++ks) {
            bf16x8 af[4], bfr[4];
            #pragma unroll
            for (int m = 0; m < 4; ++m) {
                int row = wr * 64 + m * 16 + lj;
                int c = ks * 4 + lg;
                af[m] = *(const bf16x8*)((const char*)As + row * 128 +
                                         ((c ^ (row & 7)) * 16));
            }
            #pragma unroll
            for (int nn = 0; nn < 4; ++nn) {
                int row = wc * 64 + nn * 16 + lj;
                int c = ks * 4 + lg;
                bfr[nn] = *(const bf16x8*)((const char*)Bs + row * 128 +
                                           ((c ^ (row & 7)) * 16));
            }
            #pragma unroll
            for (int m = 0; m < 4; ++m)
                #pragma unroll
                for (int nn = 0; nn < 4; ++nn)
                    acc[m][nn] = __builtin_amdgcn_mfma_f32_16x16x32_bf16(
                                     af[m], bfr[nn], acc[m][nn], 0, 0, 0);
        }
    }

    // direct store epilogue (coalesced within 16-lane groups; L2 merges lines)
    #pragma unroll
    for (int m = 0; m < 4; ++m) {
        #pragma unroll
        for (int rr = 0; rr < 4; ++rr) {
            int row = m0 + wr * 64 + m * 16 + 4 * lg + rr;
            #pragma unroll
            for (int nn = 0; nn < 4; ++nn) {
                int col = n0 + wc * 64 + nn * 16 + lj;
                float v = acc[m][nn][rr];
                if constexpr (MODE == 2) {
                    xo[(size_t)row * 1024 + col] = v + hres[(size_t)row * 1024 + col];
                } else if constexpr (MODE == 0) {
                    outK[(size_t)row * 1024 + col] = f2bf(v);
                } else {
                    if (n0 < 1024) outK[(size_t)row * 1024 + col] = f2bf(v);
                    else           outV[(size_t)row * 1024 + (col - 1024)] = f2bf(v);
                }
            }
        }
    }
}

// ---------------------------------------------------------------------------
// DPFP feature kernel: thread = one (b,h,seq) row; g[128] packed bf16 pairs in
// registers, fully-unrolled static indexing; 384 features -> 768B contiguous.
// tid < 65536: q rows; else k rows.
// ---------------------------------------------------------------------------
#define GEXT(a) ((a) < 64 ? ((a) & 1 ? __builtin_bit_cast(float, glo[(a) >> 1] & 0xffff0000u) \
                                     : __builtin_bit_cast(float, glo[(a) >> 1] << 16)) \
                          : ((a) & 1 ? __builtin_bit_cast(float, ghi[((a) - 64) >> 1] & 0xffff0000u) \
                                     : __builtin_bit_cast(float, ghi[((a) - 64) >> 1] << 16)))

__global__ __launch_bounds__(256)
void dpfp_kernel(const unsigned short* __restrict__ qraw,
                 const unsigned short* __restrict__ kraw,
                 unsigned short* __restrict__ qf, unsigned short* __restrict__ kf)
{
    int tid = blockIdx.x * 256 + threadIdx.x;
    const unsigned short* src;
    unsigned short* dst;
    if (tid < 65536) {
        int i = tid & 511, bh = tid >> 9, b = bh >> 4, hh = bh & 15;
        src = qraw + (size_t)(i * 8 + b) * 1024 + hh * 64;
        dst = qf + (size_t)tid * NF;
    } else {
        int t2 = tid - 65536;
        int j = t2 & 1023, bh = t2 >> 10, b = bh >> 4, hh = bh & 15;
        src = kraw + (size_t)(j * 8 + b) * 1024 + hh * 64;
        dst = kf + (size_t)t2 * NF;
    }

    unsigned int xr[32];
    #pragma unroll
    for (int c = 0; c < 8; ++c) {
        u32x4 v = *(const u32x4*)(src + c * 8);
        xr[c * 4 + 0] = v[0]; xr[c * 4 + 1] = v[1];
        xr[c * 4 + 2] = v[2]; xr[c * 4 + 3] = v[3];
    }

    unsigned int glo[32], ghi[32];
    #pragma unroll
    for (int p = 0; p < 32; ++p) {
        float x0 = __builtin_bit_cast(float, xr[p] << 16);
        float x1 = __builtin_bit_cast(float, xr[p] & 0xffff0000u);
        float a0 = fmaxf(x0, 0.f), a1 = fmaxf(x1, 0.f);
        float b0 = fmaxf(-x0, 0.f), b1 = fmaxf(-x1, 0.f);
        asm("v_cvt_pk_bf16_f32 %0, %1, %2" : "=v"(glo[p]) : "v"(a0), "v"(a1));
        asm("v_cvt_pk_bf16_f32 %0, %1, %2" : "=v"(ghi[p]) : "v"(b0), "v"(b1));
    }

    #pragma unroll
    for (int f0 = 0; f0 < NF; f0 += 8) {
        unsigned int w4[4];
        #pragma unroll
        for (int q2 = 0; q2 < 4; ++q2) {
            const int f  = f0 + q2 * 2;
            const int r0 = (f >> 7) + 1,       t0 = f & 127,       u0 = (t0 - r0) & 127;
            const int r1 = ((f + 1) >> 7) + 1, t1 = (f + 1) & 127, u1 = (t1 - r1) & 127;
            float p0 = GEXT(t0) * GEXT(u0);
            float p1 = GEXT(t1) * GEXT(u1);
            asm("v_cvt_pk_bf16_f32 %0, %1, %2" : "=v"(w4[q2]) : "v"(p0), "v"(p1));
        }
        u32x4 st = {w4[0], w4[1], w4[2], w4[3]};
        *(u32x4*)(dst + f0) = st;
    }
}

// ---------------------------------------------------------------------------
// V transpose: v_raw [8192=(j,b)][1024=(h,d)] bf16 -> vt [b,h][d][KLEN] bf16.
// Block = (jc, h, b): 256 j-rows staged to LDS, transposed write-out.
// ---------------------------------------------------------------------------
__global__ __launch_bounds__(256)
void vtrans_kernel(const unsigned short* __restrict__ vraw,
                   unsigned short* __restrict__ vt)
{
    __shared__ unsigned short S[256][72];
    const int t  = threadIdx.x;
    const int jc = blockIdx.x, hh = blockIdx.y, b = blockIdx.z;
    const unsigned short* src = vraw + (size_t)((jc * 256 + t) * 8 + b) * 1024 + hh * 64;
    #pragma unroll
    for (int c = 0; c < 8; ++c)
        *(u32x4*)&S[t][c * 8] = *(const u32x4*)(src + c * 8);
    __syncthreads();
    const int d = t >> 2, qq = t & 3;
    unsigned short* dst = vt + ((size_t)(b * NH + hh) * HD + d) * KLEN + jc * 256 + qq * 64;
    #pragma unroll
    for (int c8 = 0; c8 < 8; ++c8) {
        u16x8 o;
        #pragma unroll
        for (int e = 0; e < 8; ++e) o[e] = S[qq * 64 + c8 * 8 + e][d];
        *(u16x8*)(dst + c8 * 8) = o;
    }
}

// ---------------------------------------------------------------------------
// MFMA attention, K/V LDS-staged per j-tile (shared by 4 waves).
// Grid (it, n, b): blocks sharing a (b,n) K-panel are dispatch-adjacent.
// ---------------------------------------------------------------------------
__global__ __launch_bounds__(256)
void attn_mfma_kernel(const unsigned short* __restrict__ qf,
                      const unsigned short* __restrict__ kf,
                      const unsigned short* __restrict__ vt,
                      unsigned short* __restrict__ avec)
{
    __shared__ unsigned short Ks[64 * 384];   // 48KB, rows 768B, swizzled
    __shared__ unsigned short Vs[64 * 64];    // 8KB, rows(d) 128B, swizzled
    __shared__ float Ss[64][68];

    const int t  = threadIdx.x;
    const int w  = t >> 6;
    const int l  = t & 63;
    const int lj = l & 15;
    const int lg = l >> 4;
    const int it = blockIdx.x;
    const int n  = blockIdx.y;
    const int b  = blockIdx.z;
    const int i0 = it * 64 + w * 16;

    const unsigned short* qbase = qf + (size_t)(b * NH + n) * QLEN * NF;
    const unsigned short* kbase = kf + (size_t)(b * NH + n) * KLEN * NF;
    const unsigned short* vbase = vt + (size_t)(b * NH + n) * HD * KLEN;

    int koff[12];
    #pragma unroll
    for (int u = 0; u < 12; ++u) {
        int L   = (w * 12 + u) * 1024 + l * 16;
        int row = L / 768;
        int cb  = (L - row * 768) >> 4;
        int swz = (cb & ~7) | ((cb & 7) ^ (row & 7));
        koff[u] = row * 768 + swz * 16;
    }
    int voff[2];
    #pragma unroll
    for (int uu = 0; uu < 2; ++uu) {
        int d = (w * 2 + uu) * 8 + (l >> 3);
        int c = (l & 7) ^ (l >> 3);
        voff[uu] = d * (KLEN * 2) + c * 16;
    }

    bf16x8 qfr[12];
    {
        const unsigned short* qrow = qbase + (size_t)(i0 + lj) * NF + lg * 8;
        #pragma unroll
        for (int ks = 0; ks < 12; ++ks)
            qfr[ks] = *(const bf16x8*)(qrow + ks * 32);
    }

    v4f num[4] = {};
    float den[4] = {0.f, 0.f, 0.f, 0.f};

    const int jt_end = it + 8;
    for (int jt = 0; jt <= jt_end; ++jt) {
        const int j0 = jt * 64;
        __syncthreads();
        const char* ktile = (const char*)(kbase + (size_t)j0 * NF);
        #pragma unroll
        for (int u = 0; u < 12; ++u)
            gll16(ktile + koff[u], (char*)Ks + (w * 12 + u) * 1024);
        const char* vtile = (const char*)vbase + j0 * 2;
        #pragma unroll
        for (int uu = 0; uu < 2; ++uu)
            gll16(vtile + voff[uu], (char*)Vs + (w * 2 + uu) * 1024);
        __syncthreads();

        v4f sacc[4] = {};
        #pragma unroll
        for (int jf = 0; jf < 4; ++jf) {
            const int row = jf * 16 + lj;
            const char* krow = (const char*)Ks + row * 768;
            #pragma unroll
            for (int ks = 0; ks < 12; ++ks) {
                int c   = ks * 4 + lg;
                int swz = (c & ~7) | ((c & 7) ^ (row & 7));
                bf16x8 kfr = *(const bf16x8*)(krow + swz * 16);
                sacc[jf] = __builtin_amdgcn_mfma_f32_16x16x32_bf16(
                               qfr[ks], kfr, sacc[jf], 0, 0, 0);
            }
        }

        const bool diag = (jt == jt_end);
        #pragma unroll
        for (int jf = 0; jf < 4; ++jf) {
            #pragma unroll
            for (int r = 0; r < 4; ++r) {
                float sv = sacc[jf][r];
                int li  = 4 * lg + r;
                int ljj = jf * 16 + lj;
                if (diag && ljj > (w * 16 + li)) sv = 0.f;
                den[r] += sv;
                Ss[w * 16 + li][ljj] = sv;
            }
        }

        #pragma unroll
        for (int kk = 0; kk < 2; ++kk) {
            const float* prow = &Ss[w * 16 + lj][kk * 32 + lg * 8];
            v4f plo = *(const v4f*)prow;
            v4f phi = *(const v4f*)(prow + 4);
            unsigned int w0, w1, w2, w3;
            asm("v_cvt_pk_bf16_f32 %0, %1, %2" : "=v"(w0) : "v"(plo[0]), "v"(plo[1]));
            asm("v_cvt_pk_bf16_f32 %0, %1, %2" : "=v"(w1) : "v"(plo[2]), "v"(plo[3]));
            asm("v_cvt_pk_bf16_f32 %0, %1, %2" : "=v"(w2) : "v"(phi[0]), "v"(phi[1]));
            asm("v_cvt_pk_bf16_f32 %0, %1, %2" : "=v"(w3) : "v"(phi[2]), "v"(phi[3]));
            u32x4 pw = {w0, w1, w2, w3};
            bf16x8 pa = __builtin_bit_cast(bf16x8, pw);
            #pragma unroll
            for (int fd = 0; fd < 4; ++fd) {
                int row = fd * 16 + lj;
                int swz = (kk * 4 + lg) ^ (row & 7);
                bf16x8 vb = *(const bf16x8*)((const char*)Vs + row * 128 + swz * 16);
                num[fd] = __builtin_amdgcn_mfma_f32_16x16x32_bf16(
                              pa, vb, num[fd], 0, 0, 0);
            }
        }
    }

    #pragma unroll
    for (int r = 0; r < 4; ++r) {
        float v = den[r];
        v += __shfl_xor(v, 1, 16);
        v += __shfl_xor(v, 2, 16);
        v += __shfl_xor(v, 4, 16);
        v += __shfl_xor(v, 8, 16);
        den[r] = v;
    }

    #pragma unroll
    for (int r = 0; r < 4; ++r) {
        float minv = ATT_SCALE / (den[r] * ATT_SCALE + EPSV);
        int gi = i0 + 4 * lg + r;
        unsigned short* orow = avec + ((size_t)gi * BB + b) * DMODEL + n * HD;
        #pragma unroll
        for (int fd = 0; fd < 4; ++fd)
            orow[fd * 16 + lj] = f2bf(num[fd][r] * minv);
    }
}

// ---------------------------------------------------------------------------
// Row LayerNorm over DM=1024.
// ---------------------------------------------------------------------------
__global__ __launch_bounds__(256)
void ln_kernel(const float* __restrict__ x, const float* __restrict__ gamma,
               const float* __restrict__ beta, float* __restrict__ out)
{
    const int row = blockIdx.x;
    const int t = threadIdx.x;
    const float* xr = x + (size_t)row * DMODEL;
    v4f xv = *(const v4f*)(xr + (t << 2));
    float s1 = xv[0] + xv[1] + xv[2] + xv[3];
    float s2 = xv[0]*xv[0] + xv[1]*xv[1] + xv[2]*xv[2] + xv[3]*xv[3];
    #pragma unroll
    for (int off = 32; off > 0; off >>= 1) {
        s1 += __shfl_down(s1, off);
        s2 += __shfl_down(s2, off);
    }
    __shared__ float red[2][4];
    __shared__ float mv[2];
    const int wave = t >> 6;
    if ((t & 63) == 0) { red[0][wave] = s1; red[1][wave] = s2; }
    __syncthreads();
    if (t == 0) {
        float a = red[0][0] + red[0][1] + red[0][2] + red[0][3];
        float q = red[1][0] + red[1][1] + red[1][2] + red[1][3];
        float mu  = a * (1.f / DMODEL);
        float var = q * (1.f / DMODEL) - mu * mu;
        mv[0] = mu;
        mv[1] = rsqrtf(var + EPSV);
    }
    __syncthreads();
    float mu = mv[0], rs = mv[1];
    v4f gv = *(const v4f*)(gamma + (t << 2));
    v4f bv = *(const v4f*)(beta + (t << 2));
    v4f o;
    #pragma unroll
    for (int e = 0; e < 4; ++e) o[e] = (xv[e] - mu) * rs * gv[e] + bv[e];
    *(v4f*)(out + (size_t)row * DMODEL + (t << 2)) = o;
}

extern "C" void kernel_launch(void* const* d_in, const int* in_sizes, int n_in,
                              void* d_out, int out_size, void* d_ws, size_t ws_size,
                              hipStream_t stream)
{
    const float* h     = (const float*)d_in[0];
    const float* mems  = (const float*)d_in[1];
    const float* Wq    = (const float*)d_in[2];
    const float* Wkv   = (const float*)d_in[3];
    const float* Wo    = (const float*)d_in[4];
    const float* gamma = (const float*)d_in[5];
    const float* beta  = (const float*)d_in[6];
    // d_in[7] = attn_mask: causal structure computed analytically, ignored.

    char* ws = (char*)d_ws;
    unsigned short* qf   = (unsigned short*)(ws);             // [0, 50.33M)
    unsigned short* kf   = (unsigned short*)(ws + 50331648);  // [50.33M, 151.0M)
    unsigned short* kraw = (unsigned short*)(ws + 150994944); // 16.78M
    unsigned short* vt   = kraw;                              // overlay after dpfp
    unsigned short* vraw = (unsigned short*)(ws + 167772160); // 16.78M
    unsigned short* cbf  = (unsigned short*)(ws + 184549376); // 16.78M (to 201.3M)
    unsigned short* qraw = cbf;                               // overlay mems-half after mm1
    unsigned short* avec = cbf;                               // overlay after dpfp (8.4M)
    float* xws = (float*)(ws);                                // overlay qf after attn

    // bf16 weights scratch inside d_out (dead until ln_kernel rewrites it)
    unsigned short* wqb  = (unsigned short*)d_out;            // 1,048,576 el
    unsigned short* wkvb = wqb + 1048576;                     // 2,097,152 el
    unsigned short* wob  = wkvb + 2097152;                    // 1,048,576 el

    cvt_all_kernel<<<12288, 256, 0, stream>>>(h, mems, Wq, Wkv, Wo, cbf, wqb, wkvb, wob);
    // kv-proj first (consumes cbf fully), then q-proj (reads h-half, writes mems-half)
    mm128_kernel<1><<<dim3(64, 16), 256, 0, stream>>>(cbf, wkvb, nullptr, kraw, vraw, nullptr);
    mm128_kernel<0><<<dim3(32, 8), 256, 0, stream>>>(cbf + 4194304, wqb, nullptr, qraw, nullptr, nullptr);
    dpfp_kernel<<<768, 256, 0, stream>>>(qraw, kraw, qf, kf);
    vtrans_kernel<<<dim3(4, 16, 8), 256, 0, stream>>>(vraw, vt);
    attn_mfma_kernel<<<dim3(8, 16, 8), 256, 0, stream>>>(qf, kf, vt, avec);
    mm128_kernel<2><<<dim3(32, 8), 256, 0, stream>>>(avec, wob, h, nullptr, nullptr, xws);
    ln_kernel<<<4096, 256, 0, stream>>>(xws, gamma, beta, (float*)d_out);
}

// Round 5
// 490.074 us; speedup vs baseline: 1.1925x; 1.1925x over previous
//
#include <hip/hip_runtime.h>

#define QLEN 512
#define MLEN 512
#define KLEN 1024
#define BB   8
#define DMODEL 1024
#define NH   16
#define HD   64
#define NF   384
#define ATT_SCALE 0.125f
#define EPSV 1e-5f

typedef float v4f __attribute__((ext_vector_type(4)));
typedef short bf16x8 __attribute__((ext_vector_type(8)));
typedef unsigned int u32x4 __attribute__((ext_vector_type(4)));
typedef unsigned short u16x8 __attribute__((ext_vector_type(8)));

__device__ __forceinline__ unsigned short f2bf(float f) {
    unsigned int x = __builtin_bit_cast(unsigned int, f);
    x += 0x7fffu + ((x >> 16) & 1u);
    return (unsigned short)(x >> 16);
}

__device__ __forceinline__ void gll16(const void* g, void* l) {
    __builtin_amdgcn_global_load_lds(
        (const __attribute__((address_space(1))) unsigned int*)g,
        (__attribute__((address_space(3))) unsigned int*)l, 16, 0, 0);
}

// ---------------------------------------------------------------------------
// Fused f32->bf16 converts: mems+h -> cbf (c matrix), weights -> bf16 scratch
// ---------------------------------------------------------------------------
__global__ __launch_bounds__(256)
void cvt_all_kernel(const float* __restrict__ h, const float* __restrict__ mems,
                    const float* __restrict__ Wq, const float* __restrict__ Wkv,
                    const float* __restrict__ Wo,
                    unsigned short* __restrict__ cbf, unsigned short* __restrict__ wqb,
                    unsigned short* __restrict__ wkvb, unsigned short* __restrict__ wob)
{
    int blk = blockIdx.x;
    const float* src; unsigned short* dst; int base;
    if (blk < 4096)       { src = mems; dst = cbf;           base = blk; }
    else if (blk < 8192)  { src = h;    dst = cbf + 4194304; base = blk - 4096; }
    else if (blk < 9216)  { src = Wq;   dst = wqb;           base = blk - 8192; }
    else if (blk < 11264) { src = Wkv;  dst = wkvb;          base = blk - 9216; }
    else                  { src = Wo;   dst = wob;           base = blk - 11264; }
    int i = (base * 256 + threadIdx.x) * 4;
    v4f v = *(const v4f*)(src + i);
    unsigned int p0, p1;
    asm("v_cvt_pk_bf16_f32 %0, %1, %2" : "=v"(p0) : "v"(v[0]), "v"(v[1]));
    asm("v_cvt_pk_bf16_f32 %0, %1, %2" : "=v"(p1) : "v"(v[2]), "v"(v[3]));
    uint2 u; u.x = p0; u.y = p1;
    *(uint2*)(dst + i) = u;
}

// ---------------------------------------------------------------------------
// Pure MFMA GEMM, 128x128 tile, BK=64, 4 waves (each 64x64 = 4x4 frags).
// MODE 0: out = q_raw bf16; MODE 1: outK/outV = k_raw/v_raw bf16;
// MODE 2: xo f32 = C + hres
// ---------------------------------------------------------------------------
template<int MODE>
__global__ __launch_bounds__(256)
void mm128_kernel(const unsigned short* __restrict__ Abf,
                  const unsigned short* __restrict__ Bbf,
                  const float* __restrict__ hres,
                  unsigned short* __restrict__ outK,
                  unsigned short* __restrict__ outV,
                  float* __restrict__ xo)
{
    __shared__ unsigned short As[128 * 64];
    __shared__ unsigned short Bs[128 * 64];

    const int t  = threadIdx.x;
    const int w  = t >> 6;
    const int l  = t & 63;
    const int lj = l & 15;
    const int lg = l >> 4;
    const int m0 = blockIdx.x * 128;
    const int n0 = blockIdx.y * 128;
    const int wr = w >> 1, wc = w & 1;
    const int rsub = l >> 3;
    const int csw  = ((l & 7) ^ rsub) * 16;

    v4f acc[4][4] = {};

    for (int s = 0; s < 16; ++s) {
        const int k0b = s * 128;
        __syncthreads();
        #pragma unroll
        for (int u = 0; u < 4; ++u) {
            int ra = w * 32 + u * 8;
            gll16((const char*)Abf + (size_t)(m0 + ra + rsub) * 2048 + k0b + csw,
                  (char*)As + ra * 128);
            gll16((const char*)Bbf + (size_t)(n0 + ra + rsub) * 2048 + k0b + csw,
                  (char*)Bs + ra * 128);
        }
        __syncthreads();
        #pragma unroll
        for (int ks = 0; ks < 2; ++ks) {
            bf16x8 af[4], bfr[4];
            #pragma unroll
            for (int m = 0; m < 4; ++m) {
                int row = wr * 64 + m * 16 + lj;
                int c = ks * 4 + lg;
                af[m] = *(const bf16x8*)((const char*)As + row * 128 +
                                         ((c ^ (row & 7)) * 16));
            }
            #pragma unroll
            for (int nn = 0; nn < 4; ++nn) {
                int row = wc * 64 + nn * 16 + lj;
                int c = ks * 4 + lg;
                bfr[nn] = *(const bf16x8*)((const char*)Bs + row * 128 +
                                           ((c ^ (row & 7)) * 16));
            }
            #pragma unroll
            for (int m = 0; m < 4; ++m)
                #pragma unroll
                for (int nn = 0; nn < 4; ++nn)
                    acc[m][nn] = __builtin_amdgcn_mfma_f32_16x16x32_bf16(
                                     af[m], bfr[nn], acc[m][nn], 0, 0, 0);
        }
    }

    #pragma unroll
    for (int m = 0; m < 4; ++m) {
        #pragma unroll
        for (int rr = 0; rr < 4; ++rr) {
            int row = m0 + wr * 64 + m * 16 + 4 * lg + rr;
            #pragma unroll
            for (int nn = 0; nn < 4; ++nn) {
                int col = n0 + wc * 64 + nn * 16 + lj;
                float v = acc[m][nn][rr];
                if constexpr (MODE == 2) {
                    xo[(size_t)row * 1024 + col] = v + hres[(size_t)row * 1024 + col];
                } else if constexpr (MODE == 0) {
                    outK[(size_t)row * 1024 + col] = f2bf(v);
                } else {
                    if (n0 < 1024) outK[(size_t)row * 1024 + col] = f2bf(v);
                    else           outV[(size_t)row * 1024 + (col - 1024)] = f2bf(v);
                }
            }
        }
    }
}

// ---------------------------------------------------------------------------
// DPFP feature kernel. Output layout is CHUNK-BLOCKED:
//   panel[bh] -> rowblk(64 rows) -> chunk(48 of 8 feats) -> row(64) -> 8 bf16
// so each store instruction writes 64 lanes x 16B = 1KB contiguous.
// ---------------------------------------------------------------------------
#define GEXT(a) ((a) < 64 ? ((a) & 1 ? __builtin_bit_cast(float, glo[(a) >> 1] & 0xffff0000u) \
                                     : __builtin_bit_cast(float, glo[(a) >> 1] << 16)) \
                          : ((a) & 1 ? __builtin_bit_cast(float, ghi[((a) - 64) >> 1] & 0xffff0000u) \
                                     : __builtin_bit_cast(float, ghi[((a) - 64) >> 1] << 16)))

__global__ __launch_bounds__(256)
void dpfp_kernel(const unsigned short* __restrict__ qraw,
                 const unsigned short* __restrict__ kraw,
                 unsigned short* __restrict__ qf, unsigned short* __restrict__ kf)
{
    int tid = blockIdx.x * 256 + threadIdx.x;
    const unsigned short* src;
    unsigned short* dst;
    if (tid < 65536) {
        int i = tid & 511, bh = tid >> 9, b = bh >> 4, hh = bh & 15;
        src = qraw + (size_t)(i * 8 + b) * 1024 + hh * 64;
        dst = qf + (size_t)bh * (QLEN * NF) + (i >> 6) * (64 * NF) + (i & 63) * 8;
    } else {
        int t2 = tid - 65536;
        int j = t2 & 1023, bh = t2 >> 10, b = bh >> 4, hh = bh & 15;
        src = kraw + (size_t)(j * 8 + b) * 1024 + hh * 64;
        dst = kf + (size_t)bh * (KLEN * NF) + (j >> 6) * (64 * NF) + (j & 63) * 8;
    }

    unsigned int xr[32];
    #pragma unroll
    for (int c = 0; c < 8; ++c) {
        u32x4 v = *(const u32x4*)(src + c * 8);
        xr[c * 4 + 0] = v[0]; xr[c * 4 + 1] = v[1];
        xr[c * 4 + 2] = v[2]; xr[c * 4 + 3] = v[3];
    }

    unsigned int glo[32], ghi[32];
    #pragma unroll
    for (int p = 0; p < 32; ++p) {
        float x0 = __builtin_bit_cast(float, xr[p] << 16);
        float x1 = __builtin_bit_cast(float, xr[p] & 0xffff0000u);
        float a0 = fmaxf(x0, 0.f), a1 = fmaxf(x1, 0.f);
        float b0 = fmaxf(-x0, 0.f), b1 = fmaxf(-x1, 0.f);
        asm("v_cvt_pk_bf16_f32 %0, %1, %2" : "=v"(glo[p]) : "v"(a0), "v"(a1));
        asm("v_cvt_pk_bf16_f32 %0, %1, %2" : "=v"(ghi[p]) : "v"(b0), "v"(b1));
    }

    #pragma unroll
    for (int f0 = 0; f0 < NF; f0 += 8) {
        unsigned int w4[4];
        #pragma unroll
        for (int q2 = 0; q2 < 4; ++q2) {
            const int f  = f0 + q2 * 2;
            const int r0 = (f >> 7) + 1,       t0 = f & 127,       u0 = (t0 - r0) & 127;
            const int r1 = ((f + 1) >> 7) + 1, t1 = (f + 1) & 127, u1 = (t1 - r1) & 127;
            float p0 = GEXT(t0) * GEXT(u0);
            float p1 = GEXT(t1) * GEXT(u1);
            asm("v_cvt_pk_bf16_f32 %0, %1, %2" : "=v"(w4[q2]) : "v"(p0), "v"(p1));
        }
        u32x4 st = {w4[0], w4[1], w4[2], w4[3]};
        *(u32x4*)(dst + (f0 >> 3) * 512) = st;   // chunk-major, 1KB coalesced
    }
}

// ---------------------------------------------------------------------------
// V transpose: v_raw [8192=(j,b)][1024=(h,d)] bf16 -> vt [b,h][d][KLEN] bf16.
// ---------------------------------------------------------------------------
__global__ __launch_bounds__(256)
void vtrans_kernel(const unsigned short* __restrict__ vraw,
                   unsigned short* __restrict__ vt)
{
    __shared__ unsigned short S[256][72];
    const int t  = threadIdx.x;
    const int jc = blockIdx.x, hh = blockIdx.y, b = blockIdx.z;
    const unsigned short* src = vraw + (size_t)((jc * 256 + t) * 8 + b) * 1024 + hh * 64;
    #pragma unroll
    for (int c = 0; c < 8; ++c)
        *(u32x4*)&S[t][c * 8] = *(const u32x4*)(src + c * 8);
    __syncthreads();
    const int d = t >> 2, qq = t & 3;
    unsigned short* dst = vt + ((size_t)(b * NH + hh) * HD + d) * KLEN + jc * 256 + qq * 64;
    #pragma unroll
    for (int c8 = 0; c8 < 8; ++c8) {
        u16x8 o;
        #pragma unroll
        for (int e = 0; e < 8; ++e) o[e] = S[qq * 64 + c8 * 8 + e][d];
        *(u16x8*)(dst + c8 * 8) = o;
    }
}

// ---------------------------------------------------------------------------
// MFMA attention, K/V LDS-staged per j-tile. 1D grid, panel-grouped XCD
// swizzle: bid = P%8 + 8*it + 64*(P/8), P = b*16+n — the 8 i-tile blocks of
// one panel are consecutive on one XCD (L2 reuse of the K/V panel).
// qf/kf are chunk-blocked (see dpfp_kernel).
// ---------------------------------------------------------------------------
__global__ __launch_bounds__(256)
void attn_mfma_kernel(const unsigned short* __restrict__ qf,
                      const unsigned short* __restrict__ kf,
                      const unsigned short* __restrict__ vt,
                      unsigned short* __restrict__ avec)
{
    __shared__ unsigned short Ks[64 * 384];   // rows 768B, chunk^row&7 swizzle
    __shared__ unsigned short Vs[64 * 64];
    __shared__ float Ss[64][68];

    const int t  = threadIdx.x;
    const int w  = t >> 6;
    const int l  = t & 63;
    const int lj = l & 15;
    const int lg = l >> 4;

    const int bid = blockIdx.x;
    const int P   = (bid & 7) + ((bid >> 6) << 3);  // panel 0..127
    const int it  = (bid >> 3) & 7;
    const int n   = P & 15;
    const int b   = P >> 4;
    const int i0w = w * 16;                         // row within i-tile

    const unsigned short* qpan = qf + (size_t)P * (QLEN * NF) + it * (64 * NF);
    const unsigned short* kbase = kf + (size_t)P * (KLEN * NF);
    const unsigned short* vbase = vt + (size_t)P * HD * KLEN;

    // K staging source offsets: LDS slot L16=(w*12+u)*64+l holds (row, c_lds);
    // source chunk cg = unXOR(c_lds); global 16B index = cg*64 + row.
    int koff[12];
    #pragma unroll
    for (int u = 0; u < 12; ++u) {
        int L16 = (w * 12 + u) * 64 + l;
        int row = L16 / 48;
        int c   = L16 - row * 48;
        int cg  = (c & ~7) | ((c & 7) ^ (row & 7));
        koff[u] = (cg * 64 + row) * 16;
    }
    int voff[2];
    #pragma unroll
    for (int uu = 0; uu < 2; ++uu) {
        int d = (w * 2 + uu) * 8 + (l >> 3);
        int c = (l & 7) ^ (l >> 3);
        voff[uu] = d * (KLEN * 2) + c * 16;
    }

    // Q fragments from chunk-blocked layout: 16 lanes read 256B contiguous
    bf16x8 qfr[12];
    {
        const unsigned short* qrow = qpan + (i0w + lj) * 8;
        #pragma unroll
        for (int ks = 0; ks < 12; ++ks)
            qfr[ks] = *(const bf16x8*)(qrow + (ks * 4 + lg) * 512);
    }

    v4f num[4] = {};
    float den[4] = {0.f, 0.f, 0.f, 0.f};

    const int jt_end = it + 8;
    for (int jt = 0; jt <= jt_end; ++jt) {
        __syncthreads();
        const char* ktile = (const char*)(kbase + (size_t)jt * (64 * NF));
        #pragma unroll
        for (int u = 0; u < 12; ++u)
            gll16(ktile + koff[u], (char*)Ks + (w * 12 + u) * 1024);
        const char* vtile = (const char*)vbase + jt * 128;
        #pragma unroll
        for (int uu = 0; uu < 2; ++uu)
            gll16(vtile + voff[uu], (char*)Vs + (w * 2 + uu) * 1024);
        __syncthreads();

        v4f sacc[4] = {};
        #pragma unroll
        for (int jf = 0; jf < 4; ++jf) {
            const int row = jf * 16 + lj;
            const char* krow = (const char*)Ks + row * 768;
            #pragma unroll
            for (int ks = 0; ks < 12; ++ks) {
                int c   = ks * 4 + lg;
                int swz = (c & ~7) | ((c & 7) ^ (row & 7));
                bf16x8 kfr = *(const bf16x8*)(krow + swz * 16);
                sacc[jf] = __builtin_amdgcn_mfma_f32_16x16x32_bf16(
                               qfr[ks], kfr, sacc[jf], 0, 0, 0);
            }
        }

        const bool diag = (jt == jt_end);
        #pragma unroll
        for (int jf = 0; jf < 4; ++jf) {
            #pragma unroll
            for (int r = 0; r < 4; ++r) {
                float sv = sacc[jf][r];
                int li  = 4 * lg + r;
                int ljj = jf * 16 + lj;
                if (diag && ljj > (w * 16 + li)) sv = 0.f;
                den[r] += sv;
                Ss[w * 16 + li][ljj] = sv;
            }
        }

        #pragma unroll
        for (int kk = 0; kk < 2; ++kk) {
            const float* prow = &Ss[w * 16 + lj][kk * 32 + lg * 8];
            v4f plo = *(const v4f*)prow;
            v4f phi = *(const v4f*)(prow + 4);
            unsigned int w0, w1, w2, w3;
            asm("v_cvt_pk_bf16_f32 %0, %1, %2" : "=v"(w0) : "v"(plo[0]), "v"(plo[1]));
            asm("v_cvt_pk_bf16_f32 %0, %1, %2" : "=v"(w1) : "v"(plo[2]), "v"(plo[3]));
            asm("v_cvt_pk_bf16_f32 %0, %1, %2" : "=v"(w2) : "v"(phi[0]), "v"(phi[1]));
            asm("v_cvt_pk_bf16_f32 %0, %1, %2" : "=v"(w3) : "v"(phi[2]), "v"(phi[3]));
            u32x4 pw = {w0, w1, w2, w3};
            bf16x8 pa = __builtin_bit_cast(bf16x8, pw);
            #pragma unroll
            for (int fd = 0; fd < 4; ++fd) {
                int row = fd * 16 + lj;
                int swz = (kk * 4 + lg) ^ (row & 7);
                bf16x8 vb = *(const bf16x8*)((const char*)Vs + row * 128 + swz * 16);
                num[fd] = __builtin_amdgcn_mfma_f32_16x16x32_bf16(
                              pa, vb, num[fd], 0, 0, 0);
            }
        }
    }

    #pragma unroll
    for (int r = 0; r < 4; ++r) {
        float v = den[r];
        v += __shfl_xor(v, 1, 16);
        v += __shfl_xor(v, 2, 16);
        v += __shfl_xor(v, 4, 16);
        v += __shfl_xor(v, 8, 16);
        den[r] = v;
    }

    #pragma unroll
    for (int r = 0; r < 4; ++r) {
        float minv = ATT_SCALE / (den[r] * ATT_SCALE + EPSV);
        int gi = it * 64 + w * 16 + 4 * lg + r;
        unsigned short* orow = avec + ((size_t)gi * BB + b) * DMODEL + n * HD;
        #pragma unroll
        for (int fd = 0; fd < 4; ++fd)
            orow[fd * 16 + lj] = f2bf(num[fd][r] * minv);
    }
}

// ---------------------------------------------------------------------------
// Row LayerNorm over DM=1024.
// ---------------------------------------------------------------------------
__global__ __launch_bounds__(256)
void ln_kernel(const float* __restrict__ x, const float* __restrict__ gamma,
               const float* __restrict__ beta, float* __restrict__ out)
{
    const int row = blockIdx.x;
    const int t = threadIdx.x;
    const float* xr = x + (size_t)row * DMODEL;
    v4f xv = *(const v4f*)(xr + (t << 2));
    float s1 = xv[0] + xv[1] + xv[2] + xv[3];
    float s2 = xv[0]*xv[0] + xv[1]*xv[1] + xv[2]*xv[2] + xv[3]*xv[3];
    #pragma unroll
    for (int off = 32; off > 0; off >>= 1) {
        s1 += __shfl_down(s1, off);
        s2 += __shfl_down(s2, off);
    }
    __shared__ float red[2][4];
    __shared__ float mv[2];
    const int wave = t >> 6;
    if ((t & 63) == 0) { red[0][wave] = s1; red[1][wave] = s2; }
    __syncthreads();
    if (t == 0) {
        float a = red[0][0] + red[0][1] + red[0][2] + red[0][3];
        float q = red[1][0] + red[1][1] + red[1][2] + red[1][3];
        float mu  = a * (1.f / DMODEL);
        float var = q * (1.f / DMODEL) - mu * mu;
        mv[0] = mu;
        mv[1] = rsqrtf(var + EPSV);
    }
    __syncthreads();
    float mu = mv[0], rs = mv[1];
    v4f gv = *(const v4f*)(gamma + (t << 2));
    v4f bv = *(const v4f*)(beta + (t << 2));
    v4f o;
    #pragma unroll
    for (int e = 0; e < 4; ++e) o[e] = (xv[e] - mu) * rs * gv[e] + bv[e];
    *(v4f*)(out + (size_t)row * DMODEL + (t << 2)) = o;
}

extern "C" void kernel_launch(void* const* d_in, const int* in_sizes, int n_in,
                              void* d_out, int out_size, void* d_ws, size_t ws_size,
                              hipStream_t stream)
{
    const float* h     = (const float*)d_in[0];
    const float* mems  = (const float*)d_in[1];
    const float* Wq    = (const float*)d_in[2];
    const float* Wkv   = (const float*)d_in[3];
    const float* Wo    = (const float*)d_in[4];
    const float* gamma = (const float*)d_in[5];
    const float* beta  = (const float*)d_in[6];
    // d_in[7] = attn_mask: causal structure computed analytically, ignored.

    char* ws = (char*)d_ws;
    unsigned short* qf   = (unsigned short*)(ws);             // [0, 50.33M)
    unsigned short* kf   = (unsigned short*)(ws + 50331648);  // [50.33M, 151.0M)
    unsigned short* kraw = (unsigned short*)(ws + 150994944); // 16.78M
    unsigned short* vt   = kraw;                              // overlay after dpfp
    unsigned short* vraw = (unsigned short*)(ws + 167772160); // 16.78M
    unsigned short* cbf  = (unsigned short*)(ws + 184549376); // 16.78M
    unsigned short* qraw = cbf;                               // overlay mems-half after mm1
    unsigned short* avec = cbf;                               // overlay after dpfp
    float* xws = (float*)(ws);                                // overlay qf after attn

    unsigned short* wqb  = (unsigned short*)d_out;
    unsigned short* wkvb = wqb + 1048576;
    unsigned short* wob  = wkvb + 2097152;

    cvt_all_kernel<<<12288, 256, 0, stream>>>(h, mems, Wq, Wkv, Wo, cbf, wqb, wkvb, wob);
    mm128_kernel<1><<<dim3(64, 16), 256, 0, stream>>>(cbf, wkvb, nullptr, kraw, vraw, nullptr);
    mm128_kernel<0><<<dim3(32, 8), 256, 0, stream>>>(cbf + 4194304, wqb, nullptr, qraw, nullptr, nullptr);
    dpfp_kernel<<<768, 256, 0, stream>>>(qraw, kraw, qf, kf);
    vtrans_kernel<<<dim3(4, 16, 8), 256, 0, stream>>>(vraw, vt);
    attn_mfma_kernel<<<1024, 256, 0, stream>>>(qf, kf, vt, avec);
    mm128_kernel<2><<<dim3(32, 8), 256, 0, stream>>>(avec, wob, h, nullptr, nullptr, xws);
    ln_kernel<<<4096, 256, 0, stream>>>(xws, gamma, beta, (float*)d_out);
}